// Round 1
// baseline (2186.956 us; speedup 1.0000x reference)
//
#include <hip/hip_runtime.h>

// GFNO 3D p4-equivariant conv, fp32 baseline.
// x: (4, 64, 32, 64, 64), W: (16,1,16,4,3,3,3), B: (1,16,1,1,1)
// out: (4, 64, 30, 62, 62)
//
// Weight symmetrization (matches jnp.rot90(k=1, axes=(kY,kX)) then roll(+1, G)):
//   ws[k][g, ky, kx] = ws[k-1][(g-1)%4, kx, 2-ky]
// w_full[(o*4+k)][(i*4+g)][ky][kx][kt] stored in d_ws as [ic][ky][kx][oc][kt].

#define C_IN 64
#define C_OUT 64
#define D_IN 32
#define H_IN 64
#define W_IN 64
#define D_OUT 30
#define H_OUT 62
#define W_OUT 62
#define NB 4

__global__ __launch_bounds__(256) void build_w_kernel(const float* __restrict__ W,
                                                      float* __restrict__ wfull) {
    int idx = blockIdx.x * 256 + threadIdx.x;
    if (idx >= 64 * 64 * 27) return;
    // idx = (((ic*3+ky)*3+kx)*64 + oc)*3 + kt
    int kt = idx % 3;
    int oc = (idx / 3) & 63;
    int kx = (idx / 192) % 3;
    int ky = (idx / 576) % 3;
    int ic = idx / 1728;
    int o = oc >> 2, kc = oc & 3;
    int i = ic >> 2, g = ic & 3;
    int sy = ky, sx = kx, gs = g;
    for (int t = 0; t < kc; ++t) {
        int ny = sx, nx = 2 - sy;   // one rot90+roll step reads (kx, 2-ky), g-1
        sy = ny; sx = nx;
        gs = (gs + 3) & 3;
    }
    // W flat: (o, 0, i, g, ky, kx, kt)
    wfull[idx] = W[((o * 16 + i) * 4 + gs) * 27 + sy * 9 + sx * 3 + kt];
}

__global__ __launch_bounds__(256) void conv_kernel(const float* __restrict__ x,
                                                   const float* __restrict__ wfull,
                                                   const float* __restrict__ B,
                                                   float* __restrict__ out) {
    // block = (n, d, h); threads: lane=oc (64), wave=w-chunk (4 x 16 outputs)
    __shared__ float xs[9 * 68];    // 9 rows of 64 + 4 pad (zeros)
    __shared__ float wl[1728];      // weights for one ic: [ky][kx][oc][kt]

    int bid = blockIdx.x;
    int h = bid % H_OUT;
    int d = (bid / H_OUT) % D_OUT;
    int n = bid / (H_OUT * D_OUT);
    int tid = threadIdx.x;
    int oc = tid & 63;
    int chunk = tid >> 6;

    // zero the pad columns (cols 64..67 of each of 9 rows) once; staging never
    // touches them, so they stay zero across the whole ic loop.
    if (tid < 36) {
        int r = tid >> 2, c = 64 + (tid & 3);
        xs[r * 68 + c] = 0.0f;
    }

    float acc[16];
#pragma unroll
    for (int t = 0; t < 16; ++t) acc[t] = 0.0f;

    // x[((n*64+ic)*32 + (d+ky))*4096 + (h+kx)*64 + col]
    const float* xbase = x + ((size_t)(n * C_IN) * D_IN + d) * (H_IN * W_IN) + h * W_IN;

    for (int ic = 0; ic < C_IN; ++ic) {
        __syncthreads();   // protect previous iteration's reads (and pad init)
        const float4* wsrc = (const float4*)(wfull + ic * 1728);
        for (int idx = tid; idx < 576; idx += 256) {
            if (idx < 144) {                 // 9 rows x 16 float4
                int r = idx >> 4;            // ky*3+kx
                int c = idx & 15;
                int ky = r / 3, kx = r % 3;
                float4 v = *(const float4*)(xbase +
                    ((size_t)ic * D_IN + ky) * (H_IN * W_IN) + kx * W_IN + c * 4);
                ((float4*)(xs + r * 68))[c] = v;
            } else {                         // 432 float4 of weights
                int widx = idx - 144;
                ((float4*)wl)[widx] = wsrc[widx];
            }
        }
        __syncthreads();

#pragma unroll
        for (int r = 0; r < 9; ++r) {
            const float* xrow = xs + r * 68 + chunk * 16;
            float xv[18];
#pragma unroll
            for (int j = 0; j < 16; j += 4) {
                float4 v = *(const float4*)(xrow + j);
                xv[j] = v.x; xv[j + 1] = v.y; xv[j + 2] = v.z; xv[j + 3] = v.w;
            }
            xv[16] = xrow[16];
            xv[17] = xrow[17];
            float w0 = wl[r * 192 + oc * 3 + 0];
            float w1 = wl[r * 192 + oc * 3 + 1];
            float w2 = wl[r * 192 + oc * 3 + 2];
#pragma unroll
            for (int t = 0; t < 16; ++t)
                acc[t] += xv[t] * w0 + xv[t + 1] * w1 + xv[t + 2] * w2;
        }
    }

    float bias = B[oc >> 2];
    float* obase = out + ((size_t)(n * C_OUT + oc) * D_OUT + d) * (H_OUT * W_OUT)
                       + h * W_OUT + chunk * 16;
    int nw = W_OUT - chunk * 16;      // 16,16,16,14
    if (nw > 16) nw = 16;
    for (int t = 0; t < nw; ++t) obase[t] = acc[t] + bias;
}

extern "C" void kernel_launch(void* const* d_in, const int* in_sizes, int n_in,
                              void* d_out, int out_size, void* d_ws, size_t ws_size,
                              hipStream_t stream) {
    const float* x = (const float*)d_in[0];
    const float* W = (const float*)d_in[1];
    const float* B = (const float*)d_in[2];
    float* out = (float*)d_out;
    float* wfull = (float*)d_ws;   // 64*64*27 floats = 432 KB

    build_w_kernel<<<(64 * 64 * 27 + 255) / 256, 256, 0, stream>>>(W, wfull);

    int nblocks = NB * D_OUT * H_OUT;  // 7440
    conv_kernel<<<nblocks, 256, 0, stream>>>(x, wfull, B, out);
}

// Round 2
// 580.257 us; speedup vs baseline: 3.7689x; 3.7689x over previous
//
#include <hip/hip_runtime.h>
#include <hip/hip_bf16.h>

// GFNO 3D p4-equivariant conv via implicit GEMM on bf16 MFMA.
// x: (4, 64, 32, 64, 64) fp32, W: (16,1,16,4,3,3,3), B: (1,16,1,1,1)
// out: (4, 64, 30, 62, 62) fp32
//
// GEMM view: M=64 (oc), N=4*30*62*62 spatial, K=27 taps x 64 ic.
// ws layout:
//   [0, 221184)            wT  bf16 [27 tap][64 oc][64 ic]
//   [262144, +67108864)    xT  bf16 [4 nb][32 d][64 h][64 w][64 ic]
//   + ~32KB OOB-read slack (poison-valued bf16, only feeds discarded outputs)

typedef __attribute__((ext_vector_type(8))) short bf16x8;
typedef __attribute__((ext_vector_type(4))) float f32x4;

__device__ __forceinline__ void gl_lds16(const void* g, void* l) {
    __builtin_amdgcn_global_load_lds(
        (const __attribute__((address_space(1))) unsigned int*)g,
        (__attribute__((address_space(3))) unsigned int*)l, 16, 0, 0);
}

// ---- symmetrized weights -> wT[tap][oc][ic] (bf16) ----------------------
__global__ __launch_bounds__(256) void build_wT(const float* __restrict__ W,
                                                __hip_bfloat16* __restrict__ wT) {
    int idx = blockIdx.x * 256 + threadIdx.x;   // (tap*64 + oc)*64 + ic
    if (idx >= 27 * 64 * 64) return;
    int ic = idx & 63;
    int oc = (idx >> 6) & 63;
    int tap = idx >> 12;
    int kt = tap % 3, kx = (tap / 3) % 3, ky = tap / 9;
    int o = oc >> 2, kc = oc & 3, i = ic >> 2, gs = ic & 3;
    int sy = ky, sx = kx;
    for (int t = 0; t < kc; ++t) {              // ws[k][g,y,x] = ws[k-1][(g-1)%4, x, 2-y]
        int ny = sx, nx = 2 - sy;
        sy = ny; sx = nx;
        gs = (gs + 3) & 3;
    }
    wT[idx] = __float2bfloat16(W[((o * 16 + i) * 4 + gs) * 27 + sy * 9 + sx * 3 + kt]);
}

// ---- x (NCDHW fp32) -> xT[nb][d][h][w][ic] (bf16) -----------------------
__global__ __launch_bounds__(256) void transpose_x(const float* __restrict__ x,
                                                   __hip_bfloat16* __restrict__ xT) {
    __shared__ __align__(16) __hip_bfloat16 ls[64 * 72];   // [w][ic], stride 72
    int bid = blockIdx.x;                                   // (nb*32 + d)*64 + h
    int h = bid & 63, d = (bid >> 6) & 31, nb = bid >> 11;
    int tid = threadIdx.x;
    int icq = tid >> 4;       // 0..15
    int w4 = tid & 15;        // float4 index along w
#pragma unroll
    for (int rep = 0; rep < 4; ++rep) {
        int ic = icq + rep * 16;
        float4 v = *(const float4*)(x + ((((size_t)nb * 64 + ic) * 32 + d) * 64 + h) * 64 + w4 * 4);
        ls[(w4 * 4 + 0) * 72 + ic] = __float2bfloat16(v.x);
        ls[(w4 * 4 + 1) * 72 + ic] = __float2bfloat16(v.y);
        ls[(w4 * 4 + 2) * 72 + ic] = __float2bfloat16(v.z);
        ls[(w4 * 4 + 3) * 72 + ic] = __float2bfloat16(v.w);
    }
    __syncthreads();
    __hip_bfloat16* obase = xT + (((size_t)nb * 32 + d) * 64 + h) * 4096;
#pragma unroll
    for (int c = tid; c < 512; c += 256) {     // 512 x 16B chunks
        int ww = c >> 3, icc = c & 7;
        bf16x8 v = *(const bf16x8*)(ls + ww * 72 + icc * 8);
        *(bf16x8*)(obase + ww * 64 + icc * 8) = v;
    }
}

// ---- implicit GEMM conv -------------------------------------------------
// block: 64 oc x 256 spatial (4 h-rows x 64 w), wave w owns h-row w.
// K-loop: kk = tap*2 + ich (ich = 32-ic half), BK=32.
__global__ __launch_bounds__(256, 2) void conv_mfma(const __hip_bfloat16* __restrict__ xT,
                                                    const __hip_bfloat16* __restrict__ wT,
                                                    const float* __restrict__ Bp,
                                                    float* __restrict__ out) {
    __shared__ __align__(16) short sA[4 * 64 * 8];    // [kq][oc][8 ic]   4 KB
    __shared__ __align__(16) short sB[4 * 256 * 8];   // [kq][n][8 ic]   16 KB

    int bid = blockIdx.x;
    int ht = bid % 16;                 // h-tile of 4 rows
    int d  = (bid / 16) % 30;
    int nb = bid / 480;
    int h0 = ht * 4;

    int tid = threadIdx.x;
    int w = tid >> 6;                  // wave id = h-row and = kq for staging
    int lane = tid & 63;
    int quad = lane >> 4, col = lane & 15;

    f32x4 acc[4][4];
#pragma unroll
    for (int mt = 0; mt < 4; ++mt)
#pragma unroll
        for (int nt = 0; nt < 4; ++nt) acc[mt][nt] = (f32x4)(0.0f);

    // B-staging thread role: row = w, w' = lane
    const __hip_bfloat16* xbase0 = xT + (size_t)nb * 8388608 + (size_t)d * 262144
                                      + (size_t)h0 * 4096;
    // A-staging thread role: kq = w, oc = lane
    const __hip_bfloat16* wbase0 = wT + lane * 64 + w * 8;

    const short* pA = sA + quad * 512 + col * 8;            // + mt*128
    const short* pB = sB + quad * 2048 + (w * 64 + col) * 8; // + nt*128

    for (int kk = 0; kk < 54; ++kk) {
        int tap = kk >> 1, ich = kk & 1;
        int kt = tap % 3, kx = (tap / 3) % 3, ky = tap / 9;
        __syncthreads();   // previous MFMA frag reads done before overwrite

        const __hip_bfloat16* gb = xbase0 + ky * 262144 + (w + kx) * 4096
                                          + (lane + kt) * 64 + ich * 32;
        gl_lds16(gb,      (char*)sB + w * 1024);
        gl_lds16(gb + 8,  (char*)sB + 4096  + w * 1024);
        gl_lds16(gb + 16, (char*)sB + 8192  + w * 1024);
        gl_lds16(gb + 24, (char*)sB + 12288 + w * 1024);
        gl_lds16(wbase0 + tap * 4096 + ich * 32, (char*)sA + w * 1024);

        __syncthreads();   // staging complete (vmcnt drained by barrier)

        bf16x8 af[4], bfr[4];
#pragma unroll
        for (int mt = 0; mt < 4; ++mt) af[mt] = *(const bf16x8*)(pA + mt * 128);
#pragma unroll
        for (int nt = 0; nt < 4; ++nt) bfr[nt] = *(const bf16x8*)(pB + nt * 128);
#pragma unroll
        for (int mt = 0; mt < 4; ++mt)
#pragma unroll
            for (int nt = 0; nt < 4; ++nt)
                acc[mt][nt] = __builtin_amdgcn_mfma_f32_16x16x32_bf16(
                    af[mt], bfr[nt], acc[mt][nt], 0, 0, 0);
    }

    // epilogue: D row = quad*4 + r (oc offset), col = n offset
    int hrow = h0 + w;
    if (hrow < 62) {
#pragma unroll
        for (int mt = 0; mt < 4; ++mt) {
            float bias = Bp[mt * 4 + quad];          // bias[oc] = B[oc>>2]
#pragma unroll
            for (int nt = 0; nt < 4; ++nt) {
                int wp = nt * 16 + col;
                if (wp < 62) {
#pragma unroll
                    for (int r = 0; r < 4; ++r) {
                        int oc = mt * 16 + quad * 4 + r;
                        out[(((size_t)nb * 64 + oc) * 30 + d) * 3844 + hrow * 62 + wp]
                            = acc[mt][nt][r] + bias;
                    }
                }
            }
        }
    }
}

extern "C" void kernel_launch(void* const* d_in, const int* in_sizes, int n_in,
                              void* d_out, int out_size, void* d_ws, size_t ws_size,
                              hipStream_t stream) {
    const float* x = (const float*)d_in[0];
    const float* W = (const float*)d_in[1];
    const float* Bp = (const float*)d_in[2];
    float* out = (float*)d_out;

    char* ws = (char*)d_ws;
    __hip_bfloat16* wT = (__hip_bfloat16*)ws;              // 221,184 B
    __hip_bfloat16* xT = (__hip_bfloat16*)(ws + 262144);   // 67,108,864 B + slack

    build_wT<<<(27 * 64 * 64 + 255) / 256, 256, 0, stream>>>(W, wT);
    transpose_x<<<4 * 32 * 64, 256, 0, stream>>>(x, xT);
    conv_mfma<<<4 * 30 * 16, 256, 0, stream>>>(xT, wT, Bp, out);
}

// Round 3
// 398.355 us; speedup vs baseline: 5.4900x; 1.4566x over previous
//
#include <hip/hip_runtime.h>
#include <hip/hip_bf16.h>

// GFNO 3D p4-equivariant conv via implicit GEMM on bf16 MFMA. R3:
//  - n-major LDS operand layouts -> fully coalesced global_load_lds staging
//    (64B-line-aligned runs; R2's 128B lane stride was the request-throughput wall)
//  - launch_bounds(256,4) for 4 blocks/CU
//  - transpose_x: 1024 fat blocks, packed bf16x2 LDS writes (stride 37), uint4 stores
//
// GEMM view: M=64 (oc), N=4*30*62*62 spatial, K=27 taps x 64 ic.
// ws layout:
//   [0, 221184)            wT  bf16 [27 tap][64 oc][64 ic]
//   [262144, +67108864)    xT  bf16 [4 nb][32 d][64 h][64 w][64 ic]
//   + ~16KB OOB-read slack (h+kx can reach 65; those outputs are discarded)

typedef __attribute__((ext_vector_type(8))) short bf16x8;
typedef __attribute__((ext_vector_type(4))) float f32x4;

__device__ __forceinline__ void gl_lds16(const void* g, void* l) {
    __builtin_amdgcn_global_load_lds(
        (const __attribute__((address_space(1))) unsigned int*)g,
        (__attribute__((address_space(3))) unsigned int*)l, 16, 0, 0);
}

// ---- symmetrized weights -> wT[tap][oc][ic] (bf16) ----------------------
__global__ __launch_bounds__(256) void build_wT(const float* __restrict__ W,
                                                __hip_bfloat16* __restrict__ wT) {
    int idx = blockIdx.x * 256 + threadIdx.x;   // (tap*64 + oc)*64 + ic
    if (idx >= 27 * 64 * 64) return;
    int ic = idx & 63;
    int oc = (idx >> 6) & 63;
    int tap = idx >> 12;
    int kt = tap % 3, kx = (tap / 3) % 3, ky = tap / 9;
    int o = oc >> 2, kc = oc & 3, i = ic >> 2, gs = ic & 3;
    int sy = ky, sx = kx;
    for (int t = 0; t < kc; ++t) {              // ws[k][g,y,x] = ws[k-1][(g-1)%4, x, 2-y]
        int ny = sx, nx = 2 - sy;
        sy = ny; sx = nx;
        gs = (gs + 3) & 3;
    }
    wT[idx] = __float2bfloat16(W[((o * 16 + i) * 4 + gs) * 27 + sy * 9 + sx * 3 + kt]);
}

// ---- x (NCDHW fp32) -> xT[nb][d][h][w][ic] (bf16) -----------------------
__device__ __forceinline__ unsigned int pack2(float a, float b) {
    union { __hip_bfloat162 h2; unsigned int u; } c;
    c.h2 = __hip_bfloat162{__float2bfloat16(a), __float2bfloat16(b)};
    return c.u;
}

__global__ __launch_bounds__(256) void transpose_x(const float* __restrict__ x,
                                                   __hip_bfloat16* __restrict__ xT) {
    __shared__ unsigned int ls[64 * 37];   // [w][ic/2] bf16x2, stride 37 (conflict-free)
    int bid = blockIdx.x;                  // (nb*32 + d)*8 + hq
    int hq = bid & 7, d = (bid >> 3) & 31, nb = bid >> 8;
    int tid = threadIdx.x;
    int w4 = tid & 15;                     // float4 index along w
    int kp = tid >> 4;                     // 0..15

    for (int hi = 0; hi < 8; ++hi) {
        int h = hq * 8 + hi;
        float4 v0[2], v1[2];
#pragma unroll
        for (int r = 0; r < 2; ++r) {
            int p = r * 16 + kp;           // ic pair index 0..31
            const float* src = x + ((((size_t)nb * 64 + 2 * p) * 32 + d) * 64 + h) * 64 + w4 * 4;
            v0[r] = *(const float4*)(src);
            v1[r] = *(const float4*)(src + 32 * 64 * 64);   // ic+1 plane
        }
        __syncthreads();   // prior iteration's reads complete
#pragma unroll
        for (int r = 0; r < 2; ++r) {
            int p = r * 16 + kp;
            ls[(w4 * 4 + 0) * 37 + p] = pack2(v0[r].x, v1[r].x);
            ls[(w4 * 4 + 1) * 37 + p] = pack2(v0[r].y, v1[r].y);
            ls[(w4 * 4 + 2) * 37 + p] = pack2(v0[r].z, v1[r].z);
            ls[(w4 * 4 + 3) * 37 + p] = pack2(v0[r].w, v1[r].w);
        }
        __syncthreads();
        __hip_bfloat16* obase = xT + (((size_t)nb * 32 + d) * 64 + h) * 4096;
#pragma unroll
        for (int c = tid; c < 512; c += 256) {
            int ww = c >> 3, icc = c & 7;
            const unsigned int* q = ls + ww * 37 + icc * 4;
            uint4 v;
            v.x = q[0]; v.y = q[1]; v.z = q[2]; v.w = q[3];
            *(uint4*)(obase + ww * 64 + icc * 8) = v;
        }
    }
}

// ---- implicit GEMM conv -------------------------------------------------
// block: 64 oc x 256 spatial (4 h-rows x 64 w), wave w owns h-row w.
// K-loop: kk = tap*2 + ich (ich = 32-ic half), BK=32.
// LDS layouts (n-major, 32-ic contiguous):
//   sA[oc][32]  <- wT[tap][oc][ich*32 + .]
//   sB[n][32]   <- xT[h0+(n>>6)+kx][(n&63)+kt][ich*32 + .]
__global__ __launch_bounds__(256, 4) void conv_mfma(const __hip_bfloat16* __restrict__ xT,
                                                    const __hip_bfloat16* __restrict__ wT,
                                                    const float* __restrict__ Bp,
                                                    float* __restrict__ out) {
    __shared__ __align__(16) short sA[64 * 32];    //  4 KB
    __shared__ __align__(16) short sB[256 * 32];   // 16 KB

    int bid = blockIdx.x;
    int ht = bid % 16;                 // h-tile of 4 rows
    int d  = (bid / 16) % 30;
    int nb = bid / 480;
    int h0 = ht * 4;

    int tid = threadIdx.x;
    int w = tid >> 6;                  // wave id = h-row
    int lane = tid & 63;
    int quad = lane >> 4, col = lane & 15;

    f32x4 acc[4][4];
#pragma unroll
    for (int mt = 0; mt < 4; ++mt)
#pragma unroll
        for (int nt = 0; nt < 4; ++nt) acc[mt][nt] = (f32x4)(0.0f);

    const __hip_bfloat16* xbase0 = xT + (size_t)nb * 8388608 + (size_t)d * 262144
                                      + (size_t)h0 * 4096;
    int lo = (lane >> 2) * 64 + (lane & 3) * 8;   // n_local*64 + kq*8

    const short* pA = sA + col * 32 + quad * 8;              // + mt*512
    const short* pB = sB + (w * 64 + col) * 32 + quad * 8;   // + nt*512

    for (int kk = 0; kk < 54; ++kk) {
        int tap = kk >> 1, ich = kk & 1;
        int kt = tap % 3, kx = (tap / 3) % 3, ky = tap / 9;
        __syncthreads();   // previous MFMA frag reads done before overwrite

        // B: wave w stages h-row w (4 x 16-wcol chunks, 1KB each, coalesced)
        const __hip_bfloat16* gB = xbase0 + ky * 262144 + (w + kx) * 4096
                                          + kt * 64 + ich * 32 + lo;
#pragma unroll
        for (int seg = 0; seg < 4; ++seg)
            gl_lds16(gB + seg * 1024, (char*)sB + (w * 64 + seg * 16) * 64);
        // A: wave w stages oc chunk w (16 oc, 1KB, coalesced)
        gl_lds16(wT + tap * 4096 + ich * 32 + w * 1024 + lo,
                 (char*)sA + w * 1024);

        __syncthreads();   // staging complete

        bf16x8 af[4], bfr[4];
#pragma unroll
        for (int mt = 0; mt < 4; ++mt) af[mt] = *(const bf16x8*)(pA + mt * 512);
#pragma unroll
        for (int nt = 0; nt < 4; ++nt) bfr[nt] = *(const bf16x8*)(pB + nt * 512);
#pragma unroll
        for (int mt = 0; mt < 4; ++mt)
#pragma unroll
            for (int nt = 0; nt < 4; ++nt)
                acc[mt][nt] = __builtin_amdgcn_mfma_f32_16x16x32_bf16(
                    af[mt], bfr[nt], acc[mt][nt], 0, 0, 0);
    }

    // epilogue: D row = quad*4 + r (oc), col = n
    int hrow = h0 + w;
    if (hrow < 62) {
#pragma unroll
        for (int mt = 0; mt < 4; ++mt) {
            float bias = Bp[mt * 4 + quad];
#pragma unroll
            for (int nt = 0; nt < 4; ++nt) {
                int wp = nt * 16 + col;
                if (wp < 62) {
#pragma unroll
                    for (int r = 0; r < 4; ++r) {
                        int oc = mt * 16 + quad * 4 + r;
                        out[(((size_t)nb * 64 + oc) * 30 + d) * 3844 + hrow * 62 + wp]
                            = acc[mt][nt][r] + bias;
                    }
                }
            }
        }
    }
}

extern "C" void kernel_launch(void* const* d_in, const int* in_sizes, int n_in,
                              void* d_out, int out_size, void* d_ws, size_t ws_size,
                              hipStream_t stream) {
    const float* x = (const float*)d_in[0];
    const float* W = (const float*)d_in[1];
    const float* Bp = (const float*)d_in[2];
    float* out = (float*)d_out;

    char* ws = (char*)d_ws;
    __hip_bfloat16* wT = (__hip_bfloat16*)ws;              // 221,184 B
    __hip_bfloat16* xT = (__hip_bfloat16*)(ws + 262144);   // 67,108,864 B + slack

    build_wT<<<(27 * 64 * 64 + 255) / 256, 256, 0, stream>>>(W, wT);
    transpose_x<<<4 * 32 * 8, 256, 0, stream>>>(x, xT);
    conv_mfma<<<4 * 30 * 16, 256, 0, stream>>>(xT, wT, Bp, out);
}